// Round 3
// baseline (1503.934 us; speedup 1.0000x reference)
//
#include <hip/hip_runtime.h>

#define NROUTES 1152
#define NCAPS   10
#define INCH    8
#define OUTCH   16
#define NBATCH  512
#define NITER   3
#define TPB     384   // 6 waves
#define RPT     3     // routes per thread: 384*3 = 1152
#define NB      2     // batches per workgroup
#define NWAVES  (TPB / 64)

// (384,3): min 3 waves/SIMD -> VGPR cap ~168, 2 blocks/CU. Live set ~135 regs
// (u[2][3][16]=96 + S[16] + bij[6] + temps) -> fits, NO spill (rounds 1-2 died to spill).
__global__ __launch_bounds__(TPB, 3)
void caps_route_kernel(const float* __restrict__ X,     // (R, B, I)
                       const float* __restrict__ W,     // (R, C, O, I)
                       float* __restrict__ OUT)         // (B, C, O)
{
    const int t    = threadIdx.x;
    const int wid  = t >> 6;
    const int lane = t & 63;
    const int c    = blockIdx.x / (NBATCH / NB);   // c-major: same-c blocks adjacent
    const int b0   = (blockIdx.x % (NBATCH / NB)) * NB;

    __shared__ float red[NWAVES][20];     // per-wave partials: [0..15]=S, [16]=Z
    __shared__ float fin[20];             // reduced totals (reused per nb, barrier-separated)
    __shared__ float redmax[NWAVES][NB];

    float u[NB][RPT][OUTCH];   // 96 VGPRs, lives whole kernel
    float bij[NB][RPT];

    // ---------------- u_hat = W[r,c] @ x[r,b] (W loaded once, used for both nb) ----------------
    #pragma unroll
    for (int j = 0; j < RPT; ++j) {
        const int r = t * RPT + j;
        const float* xp = X + ((size_t)r * NBATCH + b0) * INCH;
        float xv[NB][INCH];
        #pragma unroll
        for (int nb = 0; nb < NB; ++nb) {
            float4 a0 = *reinterpret_cast<const float4*>(xp + nb * INCH);
            float4 a1 = *reinterpret_cast<const float4*>(xp + nb * INCH + 4);
            xv[nb][0] = a0.x; xv[nb][1] = a0.y; xv[nb][2] = a0.z; xv[nb][3] = a0.w;
            xv[nb][4] = a1.x; xv[nb][5] = a1.y; xv[nb][6] = a1.z; xv[nb][7] = a1.w;
        }
        const float* wp = W + ((size_t)r * NCAPS + c) * (OUTCH * INCH);
        #pragma unroll
        for (int o = 0; o < OUTCH; ++o) {
            float4 w0 = *reinterpret_cast<const float4*>(wp + o * INCH);
            float4 w1 = *reinterpret_cast<const float4*>(wp + o * INCH + 4);
            #pragma unroll
            for (int nb = 0; nb < NB; ++nb) {
                float acc = w0.x * xv[nb][0];
                acc = fmaf(w0.y, xv[nb][1], acc);
                acc = fmaf(w0.z, xv[nb][2], acc);
                acc = fmaf(w0.w, xv[nb][3], acc);
                acc = fmaf(w1.x, xv[nb][4], acc);
                acc = fmaf(w1.y, xv[nb][5], acc);
                acc = fmaf(w1.z, xv[nb][6], acc);
                acc = fmaf(w1.w, xv[nb][7], acc);
                u[nb][j][o] = acc;
            }
        }
    }

    #pragma unroll
    for (int nb = 0; nb < NB; ++nb)
        #pragma unroll
        for (int j = 0; j < RPT; ++j)
            bij[nb][j] = 0.0f;

    // ---------------- dynamic routing ----------------
    #pragma unroll
    for (int it = 0; it < NITER; ++it) {
        // ---- block max of bij per nb (cheap: 2 regs, do in parallel) ----
        float mx[NB];
        #pragma unroll
        for (int nb = 0; nb < NB; ++nb) {
            float m = bij[nb][0];
            #pragma unroll
            for (int j = 1; j < RPT; ++j) m = fmaxf(m, bij[nb][j]);
            mx[nb] = m;
        }
        #pragma unroll
        for (int sh = 1; sh <= 32; sh <<= 1) {
            #pragma unroll
            for (int nb = 0; nb < NB; ++nb)
                mx[nb] = fmaxf(mx[nb], __shfl_xor(mx[nb], sh));
        }
        if (lane == 0) {
            #pragma unroll
            for (int nb = 0; nb < NB; ++nb) redmax[wid][nb] = mx[nb];
        }
        __syncthreads();
        #pragma unroll
        for (int nb = 0; nb < NB; ++nb) {
            float m = redmax[0][nb];
            #pragma unroll
            for (int w = 1; w < NWAVES; ++w) m = fmaxf(m, redmax[w][nb]);
            mx[nb] = m;
        }

        // ---- SEQUENTIAL per-nb: reduce S,Z -> squash -> b-update (caps reg pressure) ----
        #pragma unroll
        for (int nb = 0; nb < NB; ++nb) {
            float S[OUTCH];
            float Z = 0.0f;
            #pragma unroll
            for (int o = 0; o < OUTCH; ++o) S[o] = 0.0f;
            #pragma unroll
            for (int j = 0; j < RPT; ++j) {
                float ev = __expf(bij[nb][j] - mx[nb]);
                Z += ev;
                #pragma unroll
                for (int o = 0; o < OUTCH; ++o)
                    S[o] = fmaf(ev, u[nb][j][o], S[o]);
            }

            // wave butterfly reduce of {S[16], Z}
            #pragma unroll
            for (int sh = 1; sh <= 32; sh <<= 1) {
                Z += __shfl_xor(Z, sh);
                #pragma unroll
                for (int o = 0; o < OUTCH; ++o)
                    S[o] += __shfl_xor(S[o], sh);
            }
            if (lane == 0) {
                #pragma unroll
                for (int o = 0; o < OUTCH; ++o) red[wid][o] = S[o];
                red[wid][16] = Z;
            }
            __syncthreads();

            // cross-wave reduce: threads 0..16 each own one value
            if (t < 17) {
                float s = red[0][t];
                #pragma unroll
                for (int w = 1; w < NWAVES; ++w) s += red[w][t];
                fin[t] = s;
            }
            __syncthreads();

            // squash (every thread redundantly; broadcast from LDS)
            float v[OUTCH];
            {
                float rZ = 1.0f / fin[16];
                float n2 = 0.0f;
                #pragma unroll
                for (int o = 0; o < OUTCH; ++o) {
                    float sv = fin[o] * rZ;
                    v[o] = sv;
                    n2 = fmaf(sv, sv, n2);
                }
                float sc = sqrtf(n2) / (1.0f + n2);
                #pragma unroll
                for (int o = 0; o < OUTCH; ++o) v[o] *= sc;
            }

            if (it < NITER - 1) {
                // logit update: b += <u, v>
                #pragma unroll
                for (int j = 0; j < RPT; ++j) {
                    float d = 0.0f;
                    #pragma unroll
                    for (int o = 0; o < OUTCH; ++o)
                        d = fmaf(u[nb][j][o], v[o], d);
                    bij[nb][j] += d;
                }
            } else if (t == 0) {
                // final iteration: write v for this nb
                float* op = OUT + ((size_t)(b0 + nb) * NCAPS + c) * OUTCH;
                #pragma unroll
                for (int o = 0; o < OUTCH; o += 4)
                    *reinterpret_cast<float4*>(op + o) =
                        make_float4(v[o], v[o + 1], v[o + 2], v[o + 3]);
            }
            // No trailing barrier needed: next nb's red-writes come after this
            // nb's B2 (red readers done), and next nb's fin-writes come after
            // its own B1 (this nb's fin readers done before reaching it).
        }
    }
}

extern "C" void kernel_launch(void* const* d_in, const int* in_sizes, int n_in,
                              void* d_out, int out_size, void* d_ws, size_t ws_size,
                              hipStream_t stream) {
    const float* X = (const float*)d_in[0];            // (1152, 512, 8)
    const float* W = (const float*)d_in[1];            // (1152, 10, 16, 8)
    float* OUT     = (float*)d_out;                    // (512, 10, 16)
    dim3 grid(NCAPS * (NBATCH / NB));                  // 2560 workgroups, c-major
    caps_route_kernel<<<grid, dim3(TPB), 0, stream>>>(X, W, OUT);
}

// Round 4
// 429.303 us; speedup vs baseline: 3.5032x; 3.5032x over previous
//
#include <hip/hip_runtime.h>

#define NROUTES 1152
#define NCAPS   10
#define INCH    8
#define OUTCH   16
#define NBATCH  512
#define NITER   3
#define TPB     576          // 9 waves
#define RPT     2            // routes per thread: 576*2 = 1152
#define NB      2            // batches per block
#define NWAVES  (TPB / 64)

// u_hat lives in LDS (144 KiB), NOT registers: rounds 1-3 proved the allocator
// spills the 96-reg u array to HBM scratch (2+ GB WRITE_SIZE). Each thread
// only touches its own u entries -> no barriers on u4, standard banking.
__global__ __launch_bounds__(TPB, 1)
void caps_route_kernel(const float* __restrict__ X,     // (R, B, I)
                       const float* __restrict__ W,     // (R, C, O, I)
                       float* __restrict__ OUT)         // (B, C, O)
{
    const int t    = threadIdx.x;
    const int wid  = t >> 6;
    const int lane = t & 63;
    const int c    = blockIdx.x / (NBATCH / NB);   // c-major: same-c blocks adjacent
    const int b0   = (blockIdx.x % (NBATCH / NB)) * NB;

    __shared__ float4 u4[NB][RPT * 4][TPB];   // 2 * 8 * 576 * 16B = 144 KiB
    __shared__ float  red[NWAVES][20];        // per-wave partials: [0..15]=S, [16]=Z
    __shared__ float  fin[20];                // block-reduced totals
    __shared__ float  redmax[NWAVES][NB];

    float bij[NB][RPT];                       // routing logits (4 regs)

    // ---------------- u_hat = W[r,c] @ x[r,b] -> LDS ----------------
    #pragma unroll
    for (int j = 0; j < RPT; ++j) {
        const int r = t * RPT + j;
        const float* xp = X + ((size_t)r * NBATCH + b0) * INCH;  // 2 batches = 16 contiguous floats
        float4 xa = *reinterpret_cast<const float4*>(xp);
        float4 xb = *reinterpret_cast<const float4*>(xp + 4);
        float4 xc = *reinterpret_cast<const float4*>(xp + 8);
        float4 xd = *reinterpret_cast<const float4*>(xp + 12);
        float xv[NB][INCH] = {
            { xa.x, xa.y, xa.z, xa.w, xb.x, xb.y, xb.z, xb.w },
            { xc.x, xc.y, xc.z, xc.w, xd.x, xd.y, xd.z, xd.w } };
        const float* wp = W + ((size_t)r * NCAPS + c) * (OUTCH * INCH);
        #pragma unroll
        for (int oq = 0; oq < 4; ++oq) {           // 4 output-quads
            float4 acc[NB];
            #pragma unroll
            for (int oi = 0; oi < 4; ++oi) {
                const int o = oq * 4 + oi;
                float4 w0 = *reinterpret_cast<const float4*>(wp + o * INCH);
                float4 w1 = *reinterpret_cast<const float4*>(wp + o * INCH + 4);
                #pragma unroll
                for (int nb = 0; nb < NB; ++nb) {
                    float a = w0.x * xv[nb][0];
                    a = fmaf(w0.y, xv[nb][1], a);
                    a = fmaf(w0.z, xv[nb][2], a);
                    a = fmaf(w0.w, xv[nb][3], a);
                    a = fmaf(w1.x, xv[nb][4], a);
                    a = fmaf(w1.y, xv[nb][5], a);
                    a = fmaf(w1.z, xv[nb][6], a);
                    a = fmaf(w1.w, xv[nb][7], a);
                    reinterpret_cast<float*>(&acc[nb])[oi] = a;
                }
            }
            #pragma unroll
            for (int nb = 0; nb < NB; ++nb)
                u4[nb][j * 4 + oq][t] = acc[nb];
        }
    }

    #pragma unroll
    for (int nb = 0; nb < NB; ++nb)
        #pragma unroll
        for (int j = 0; j < RPT; ++j)
            bij[nb][j] = 0.0f;

    // ---------------- dynamic routing ----------------
    #pragma unroll
    for (int it = 0; it < NITER; ++it) {
        // ---- block max of bij per nb (stable softmax) ----
        float mx[NB];
        #pragma unroll
        for (int nb = 0; nb < NB; ++nb) {
            float m = bij[nb][0];
            #pragma unroll
            for (int j = 1; j < RPT; ++j) m = fmaxf(m, bij[nb][j]);
            mx[nb] = m;
        }
        #pragma unroll
        for (int sh = 1; sh <= 32; sh <<= 1) {
            #pragma unroll
            for (int nb = 0; nb < NB; ++nb)
                mx[nb] = fmaxf(mx[nb], __shfl_xor(mx[nb], sh));
        }
        if (lane == 0) {
            #pragma unroll
            for (int nb = 0; nb < NB; ++nb) redmax[wid][nb] = mx[nb];
        }
        __syncthreads();
        #pragma unroll
        for (int nb = 0; nb < NB; ++nb) {
            float m = redmax[0][nb];
            #pragma unroll
            for (int w = 1; w < NWAVES; ++w) m = fmaxf(m, redmax[w][nb]);
            mx[nb] = m;
        }

        // ---- sequential per-nb: reduce S,Z -> squash -> b-update ----
        #pragma unroll
        for (int nb = 0; nb < NB; ++nb) {
            float S[OUTCH];
            float Z = 0.0f;
            #pragma unroll
            for (int o = 0; o < OUTCH; ++o) S[o] = 0.0f;
            #pragma unroll
            for (int j = 0; j < RPT; ++j) {
                float ev = __expf(bij[nb][j] - mx[nb]);
                Z += ev;
                #pragma unroll
                for (int oq = 0; oq < 4; ++oq) {
                    float4 uu = u4[nb][j * 4 + oq][t];
                    S[oq * 4 + 0] = fmaf(ev, uu.x, S[oq * 4 + 0]);
                    S[oq * 4 + 1] = fmaf(ev, uu.y, S[oq * 4 + 1]);
                    S[oq * 4 + 2] = fmaf(ev, uu.z, S[oq * 4 + 2]);
                    S[oq * 4 + 3] = fmaf(ev, uu.w, S[oq * 4 + 3]);
                }
            }

            // wave butterfly reduce {S[16], Z}
            #pragma unroll
            for (int sh = 1; sh <= 32; sh <<= 1) {
                Z += __shfl_xor(Z, sh);
                #pragma unroll
                for (int o = 0; o < OUTCH; ++o)
                    S[o] += __shfl_xor(S[o], sh);
            }
            if (lane == 0) {
                #pragma unroll
                for (int o = 0; o < OUTCH; ++o) red[wid][o] = S[o];
                red[wid][16] = Z;
            }
            __syncthreads();   // B1

            if (t < 17) {
                float s = red[0][t];
                #pragma unroll
                for (int w = 1; w < NWAVES; ++w) s += red[w][t];
                fin[t] = s;
            }
            __syncthreads();   // B2

            // squash (redundant per thread; broadcast from LDS)
            float v[OUTCH];
            {
                float rZ = 1.0f / fin[16];
                float n2 = 0.0f;
                #pragma unroll
                for (int o = 0; o < OUTCH; ++o) {
                    float sv = fin[o] * rZ;
                    v[o] = sv;
                    n2 = fmaf(sv, sv, n2);
                }
                float sc = sqrtf(n2) / (1.0f + n2);
                #pragma unroll
                for (int o = 0; o < OUTCH; ++o) v[o] *= sc;
            }

            if (it < NITER - 1) {
                // logit update: b += <u, v>
                #pragma unroll
                for (int j = 0; j < RPT; ++j) {
                    float d = 0.0f;
                    #pragma unroll
                    for (int oq = 0; oq < 4; ++oq) {
                        float4 uu = u4[nb][j * 4 + oq][t];
                        d = fmaf(uu.x, v[oq * 4 + 0], d);
                        d = fmaf(uu.y, v[oq * 4 + 1], d);
                        d = fmaf(uu.z, v[oq * 4 + 2], d);
                        d = fmaf(uu.w, v[oq * 4 + 3], d);
                    }
                    bij[nb][j] += d;
                }
            } else if (t == 0) {
                float* op = OUT + ((size_t)(b0 + nb) * NCAPS + c) * OUTCH;
                #pragma unroll
                for (int o = 0; o < OUTCH; o += 4)
                    *reinterpret_cast<float4*>(op + o) =
                        make_float4(v[o], v[o + 1], v[o + 2], v[o + 3]);
            }
            // red/fin reuse across nb/it is barrier-separated by B1/B2 above.
        }
    }
}

extern "C" void kernel_launch(void* const* d_in, const int* in_sizes, int n_in,
                              void* d_out, int out_size, void* d_ws, size_t ws_size,
                              hipStream_t stream) {
    const float* X = (const float*)d_in[0];            // (1152, 512, 8)
    const float* W = (const float*)d_in[1];            // (1152, 10, 16, 8)
    float* OUT     = (float*)d_out;                    // (512, 10, 16)
    dim3 grid(NCAPS * (NBATCH / NB));                  // 2560 workgroups, c-major
    caps_route_kernel<<<grid, dim3(TPB), 0, stream>>>(X, W, OUT);
}